// Round 8
// baseline (182.038 us; speedup 1.0000x reference)
//
#include <hip/hip_runtime.h>

// Problem dims: B=16, Q=64, K=512, DQ=DK=DV=512, H=256
#define LOG2E 1.4426950408889634f
#define TWO_LOG2E 2.8853900817779268f

typedef __attribute__((ext_vector_type(8))) short short8;   // bf16x8 MFMA frag
typedef __attribute__((ext_vector_type(4))) float f32x4;    // MFMA acc

__device__ __forceinline__ float e2x(float v) {
    // exp2(2*log2(e)*v) == e^{2v}
    return __builtin_amdgcn_exp2f(v * TWO_LOG2E);
}

// Exact fp32 -> (hi,lo) bf16 split, packed: hi = top16(f) (truncation, exact),
// lo = f - hi (exactly representable in bf16: <=8 significand bits).
__device__ __forceinline__ void split2(float x, float y, unsigned& hi, unsigned& lo) {
    unsigned ux = __float_as_uint(x), uy = __float_as_uint(y);
    float hx = __uint_as_float(ux & 0xffff0000u);
    float hy = __uint_as_float(uy & 0xffff0000u);
    unsigned lx = __float_as_uint(x - hx), ly = __float_as_uint(y - hy);
    hi = (ux >> 16) | (uy & 0xffff0000u);
    lo = (lx >> 16) | (ly & 0xffff0000u);
}

// ---------------------------------------------------------------------------
// Kernel 0: W2T[n][k'] split/transposed weights, chunk-interleaved (unchanged)
// per 32-k chunk c: [c*96 +0..31]=Whi, [+32..63]=Whi, [+64..95]=Wlo.
// ---------------------------------------------------------------------------
__global__ __launch_bounds__(256) void wprep_kernel(const float* __restrict__ Wq,
                                                    const float* __restrict__ Wk,
                                                    ushort* __restrict__ Wq2T,
                                                    ushort* __restrict__ Wk2T) {
    __shared__ float T[64][65];
    const float* W  = blockIdx.z ? Wk : Wq;
    ushort* W2T     = blockIdx.z ? Wk2T : Wq2T;
    const int t  = threadIdx.x;
    const int k0 = blockIdx.x * 64;
    const int n0 = blockIdx.y * 64;
#pragma unroll
    for (int p = 0; p < 4; ++p) {
        int u  = t + p * 256;          // 0..1023
        int kk = u >> 4;               // 0..63
        int nf = (u & 15) * 4;
        float4 w = *reinterpret_cast<const float4*>(&W[(size_t)(k0 + kk) * 256 + n0 + nf]);
        T[nf + 0][kk] = w.x; T[nf + 1][kk] = w.y;
        T[nf + 2][kk] = w.z; T[nf + 3][kk] = w.w;
    }
    __syncthreads();
#pragma unroll
    for (int p = 0; p < 4; ++p) {
        int u  = t + p * 256;
        int n  = u >> 4;               // 0..63
        int kf = (u & 15) * 4;         // 0..60
        float a = T[n][kf], b = T[n][kf + 1], c = T[n][kf + 2], d = T[n][kf + 3];
        unsigned h01, l01, h23, l23;
        split2(a, b, h01, l01);
        split2(c, d, h23, l23);
        int kg = k0 + kf;
        ushort* row = W2T + (size_t)(n0 + n) * 1536 + (kg >> 5) * 96 + (kg & 31);
        uint2 hi; hi.x = h01; hi.y = h23;
        uint2 lo; lo.x = l01; lo.y = l23;
        *reinterpret_cast<uint2*>(row)      = hi;   // seg0: hi
        *reinterpret_cast<uint2*>(row + 32) = hi;   // seg1: hi
        *reinterpret_cast<uint2*>(row + 64) = lo;   // seg2: lo
    }
}

// ---------------------------------------------------------------------------
// Kernel 1 (RESTRUCTURED): fused MFMA projection, occupancy-first.
// m-tile 32 x n-tile 128; grid (288, 2) = 576 blocks (2.25/CU, ~9 waves/CU).
//   m-tiles 0..31  : Eq rows (queries);  m-tiles 32..287: Ekp rows (keys).
// 4 waves, wave-tile 32m x 32n (frags 2m x 2n of 16x16x32 bf16, 3 split terms).
// A staged fp32->split->LDS each chunk (1 float4/thread); B via
// global_load_lds 16B x 6 calls/chunk. A re-read 2x (was 4x).
// ---------------------------------------------------------------------------
__global__ __launch_bounds__(256) void mfma_proj_kernel(const float* __restrict__ queries,
                                                        const float* __restrict__ keys,
                                                        const ushort* __restrict__ Wq2T,
                                                        const ushort* __restrict__ Wk2T,
                                                        float* __restrict__ Eq,
                                                        float* __restrict__ Ekp) {
    __shared__ float smemf[7680];            // 30720 B: Ah(6144 B) + Ws(24576 B); reused as Cs
    ushort* Ah = reinterpret_cast<ushort*>(smemf);           // [32 m][96 k']
    ushort* Ws = reinterpret_cast<ushort*>(smemf) + 3072;    // [128 n][96 k']

    const int t    = threadIdx.x;
    const int mt   = blockIdx.x;             // 0..287
    const int Nb   = blockIdx.y * 128;
    const bool isQ = mt < 32;
    const int mloc = (isQ ? mt : mt - 32) * 32;   // local row base in source
    const float4* Asrc4 = reinterpret_cast<const float4*>(isQ ? queries : keys)
                        + (size_t)mloc * 128;
    const ushort* W2T = isQ ? Wq2T : Wk2T;

    const int ln15 = t & 15;
    const int q    = (t >> 4) & 3;
    const int w    = t >> 6;
    const int wn   = w * 32;                 // wave n-offset within 128

    // B global_load_lds lane mapping (6 calls x 4096 B = 24 KB/chunk)
    const char* gB[6];
#pragma unroll
    for (int i = 0; i < 6; ++i) {
        int o   = i * 4096 + t * 16;         // linear byte in Ws region
        int row = o / 192;                   // n row (192 B per row)
        int rem = o - row * 192;
        gB[i] = reinterpret_cast<const char*>(W2T) + (size_t)(Nb + row) * 3072 + rem;
    }

    f32x4 acc[2][2];
#pragma unroll
    for (int fm = 0; fm < 2; ++fm)
#pragma unroll
        for (int fn = 0; fn < 2; ++fn) acc[fm][fn] = (f32x4)0.0f;

    for (int c = 0; c < 16; ++c) {
        __syncthreads();                     // previous chunk's LDS reads done
        // --- stage A: 1 float4/thread, split, write [hi|lo|hi] ---
        {
            int m  = t >> 3;                 // 0..31
            int kf = (t & 7) * 4;            // 0..28
            float4 a = Asrc4[(size_t)m * 128 + c * 8 + (t & 7)];
            unsigned h01, l01, h23, l23;
            split2(a.x, a.y, h01, l01);
            split2(a.z, a.w, h23, l23);
            uint2 hi; hi.x = h01; hi.y = h23;
            uint2 lo; lo.x = l01; lo.y = l23;
            ushort* row = Ah + m * 96 + kf;
            *reinterpret_cast<uint2*>(row)      = hi;
            *reinterpret_cast<uint2*>(row + 32) = lo;
            *reinterpret_cast<uint2*>(row + 64) = hi;
        }
        // --- stage B: direct global->LDS ---
#pragma unroll
        for (int i = 0; i < 6; ++i) {
            __builtin_amdgcn_global_load_lds(
                reinterpret_cast<const unsigned int*>(gB[i]),
                reinterpret_cast<unsigned int*>(
                    reinterpret_cast<char*>(Ah) + 6144 + i * 4096 + (t >> 6) * 1024),
                16, 0, 0);
            gB[i] += 192;
        }
        __syncthreads();                     // drains vmcnt + lgkm
        // --- compute: 3 split-terms x (2m x 2n) MFMAs ---
#pragma unroll
        for (int s = 0; s < 3; ++s) {
            short8 af[2], bf[2];
#pragma unroll
            for (int fm = 0; fm < 2; ++fm)
                af[fm] = *reinterpret_cast<const short8*>(
                    Ah + (fm * 16 + ln15) * 96 + s * 32 + q * 8);
#pragma unroll
            for (int fn = 0; fn < 2; ++fn)
                bf[fn] = *reinterpret_cast<const short8*>(
                    Ws + (wn + fn * 16 + ln15) * 96 + s * 32 + q * 8);
#pragma unroll
            for (int fm = 0; fm < 2; ++fm)
#pragma unroll
                for (int fn = 0; fn < 2; ++fn)
                    acc[fm][fn] = __builtin_amdgcn_mfma_f32_16x16x32_bf16(
                        af[fm], bf[fn], acc[fm][fn], 0, 0, 0);
        }
    }

    // C/D layout: col = lane&15, row = quad*4 + reg  (m89/m91-verified)
    if (isQ) {
#pragma unroll
        for (int fm = 0; fm < 2; ++fm)
#pragma unroll
            for (int fn = 0; fn < 2; ++fn)
#pragma unroll
                for (int r = 0; r < 4; ++r) {
                    int row = mloc + fm * 16 + q * 4 + r;
                    int col = Nb + wn + fn * 16 + ln15;
                    Eq[(size_t)row * 256 + col] = e2x(acc[fm][fn][r]);
                }
    } else {
        __syncthreads();                     // all waves done with Ah/Ws
        float (*Cs)[33] = reinterpret_cast<float(*)[33]>(smemf);  // [n 128][m 32]
#pragma unroll
        for (int fm = 0; fm < 2; ++fm)
#pragma unroll
            for (int fn = 0; fn < 2; ++fn)
#pragma unroll
                for (int r = 0; r < 4; ++r) {
                    int m_l = fm * 16 + q * 4 + r;
                    int n_l = wn + fn * 16 + ln15;
                    Cs[n_l][m_l] = acc[fm][fn][r];
                }
        __syncthreads();
        const int b      = mloc >> 9;
        const int k0h    = (mloc & 511) >> 1;   // k-pair base (multiple of 16)
        const int h2base = Nb >> 1;
        float4* out4 = reinterpret_cast<float4*>(Ekp);
#pragma unroll
        for (int p = 0; p < 4; ++p) {
            int u   = t + p * 256;           // 0..1023
            int h2r = u >> 4;                // 0..63
            int kp  = u & 15;                // k-pair 0..15
            int kk  = kp * 2;
            float4 o;
            o.x = e2x(Cs[2 * h2r    ][kk    ]);
            o.y = e2x(Cs[2 * h2r + 1][kk    ]);
            o.z = e2x(Cs[2 * h2r    ][kk + 1]);
            o.w = e2x(Cs[2 * h2r + 1][kk + 1]);
            out4[(size_t)b * 32768 + (size_t)(h2base + h2r) * 256 + k0h + kp] = o;
        }
    }
}

// ---------------------------------------------------------------------------
// Kernel 2: scores + masked softmax -> attn[b][q][k]   (unchanged)
// ---------------------------------------------------------------------------
__global__ __launch_bounds__(256) void score_softmax_kernel(
        const float* __restrict__ Eq, const float* __restrict__ Ekp,
        const float* __restrict__ Wv, const int* __restrict__ valid_lens,
        float* __restrict__ attn) {
    __shared__ float redmA[4], redmB[4], redlA[4], redlB[4];

    const int t  = threadIdx.x;
    const int bq = blockIdx.x;        // 0..511
    const int b  = bq >> 5;
    const int q0 = (bq & 31) * 2;

    const float* eqA = Eq + (size_t)(b * 64 + q0) * 256;
    const float* eqB = eqA + 256;
    const float4* ek4 = reinterpret_cast<const float4*>(Ekp) + (size_t)b * 32768 + t;

    float accA0 = 0.f, accA1 = 0.f, accB0 = 0.f, accB1 = 0.f;
#pragma unroll 4
    for (int h2 = 0; h2 < 128; ++h2) {
        const float4 ek = ek4[h2 * 256];
        const float w0 = Wv[2 * h2];
        const float w1 = Wv[2 * h2 + 1];
        {
            const float e0 = eqA[2 * h2], e1 = eqA[2 * h2 + 1];
            float a00 = fmaf(e0, ek.x, 1.0f);
            float a10 = fmaf(e1, ek.y, 1.0f);
            float a01 = fmaf(e0, ek.z, 1.0f);
            float a11 = fmaf(e1, ek.w, 1.0f);
            float d0 = a00 * a10, d1 = a01 * a11;
            float n0 = fmaf(w1, a00, w0 * a10);
            float n1 = fmaf(w1, a01, w0 * a11);
            accA0 = fmaf(n0, __builtin_amdgcn_rcpf(d0), accA0);
            accA1 = fmaf(n1, __builtin_amdgcn_rcpf(d1), accA1);
        }
        {
            const float e0 = eqB[2 * h2], e1 = eqB[2 * h2 + 1];
            float a00 = fmaf(e0, ek.x, 1.0f);
            float a10 = fmaf(e1, ek.y, 1.0f);
            float a01 = fmaf(e0, ek.z, 1.0f);
            float a11 = fmaf(e1, ek.w, 1.0f);
            float d0 = a00 * a10, d1 = a01 * a11;
            float n0 = fmaf(w1, a00, w0 * a10);
            float n1 = fmaf(w1, a01, w0 * a11);
            accB0 = fmaf(n0, __builtin_amdgcn_rcpf(d0), accB0);
            accB1 = fmaf(n1, __builtin_amdgcn_rcpf(d1), accB1);
        }
    }
    float sA0 = -2.0f * accA0, sA1 = -2.0f * accA1;
    float sB0 = -2.0f * accB0, sB1 = -2.0f * accB1;
    const int vl = valid_lens[b];
    const int k0 = 2 * t;
    if (k0     >= vl) { sA0 = -1e6f; sB0 = -1e6f; }
    if (k0 + 1 >= vl) { sA1 = -1e6f; sB1 = -1e6f; }

    const int w = t >> 6;
    float mA = fmaxf(sA0, sA1);
    float mB = fmaxf(sB0, sB1);
#pragma unroll
    for (int off = 32; off > 0; off >>= 1) {
        mA = fmaxf(mA, __shfl_xor(mA, off));
        mB = fmaxf(mB, __shfl_xor(mB, off));
    }
    if ((t & 63) == 0) { redmA[w] = mA; redmB[w] = mB; }
    __syncthreads();
    mA = fmaxf(fmaxf(redmA[0], redmA[1]), fmaxf(redmA[2], redmA[3]));
    mB = fmaxf(fmaxf(redmB[0], redmB[1]), fmaxf(redmB[2], redmB[3]));

    float pA0 = __builtin_amdgcn_exp2f((sA0 - mA) * LOG2E);
    float pA1 = __builtin_amdgcn_exp2f((sA1 - mA) * LOG2E);
    float pB0 = __builtin_amdgcn_exp2f((sB0 - mB) * LOG2E);
    float pB1 = __builtin_amdgcn_exp2f((sB1 - mB) * LOG2E);
    float lA = pA0 + pA1, lB = pB0 + pB1;
#pragma unroll
    for (int off = 32; off > 0; off >>= 1) {
        lA += __shfl_xor(lA, off);
        lB += __shfl_xor(lB, off);
    }
    if ((t & 63) == 0) { redlA[w] = lA; redlB[w] = lB; }
    __syncthreads();
    lA = (redlA[0] + redlA[1]) + (redlA[2] + redlA[3]);
    lB = (redlB[0] + redlB[1]) + (redlB[2] + redlB[3]);
    const float invA = 1.0f / lA;
    const float invB = 1.0f / lB;

    float2* attn2 = reinterpret_cast<float2*>(attn);
    float2 oA; oA.x = pA0 * invA; oA.y = pA1 * invA;
    float2 oB; oB.x = pB0 * invB; oB.y = pB1 * invB;
    attn2[(size_t)(b * 64 + q0) * 256 + t]       = oA;
    attn2[(size_t)(b * 64 + q0 + 1) * 256 + t]   = oB;
}

// ---------------------------------------------------------------------------
// Kernel 3 (RESTRUCTURED): out[b][q][v] = attn[b][q][:] @ values[b][:][v]
// Block = (b, 8q, 128v); grid (4 v-tiles, 8 q-tiles, 16 b) = 512 (2/CU).
// K-loop: 8 chunks of 64 k; Ps[8][68] + Vs[64][132] staged in LDS with
// register-double-buffered prefetch. Wave = 2 q-rows; lane = (v4 0..31,
// ksub 0..1); shfl_xor(32) combines ksub partials.
// ---------------------------------------------------------------------------
__global__ __launch_bounds__(256) void pv_kernel(const float* __restrict__ attn,
                                                 const float* __restrict__ values,
                                                 float* __restrict__ out) {
    __shared__ __align__(16) float Ps[8][68];     //  2176 B
    __shared__ __align__(16) float Vs[64][132];   // 33792 B

    const int t  = threadIdx.x;
    const int b  = blockIdx.z;
    const int q0 = blockIdx.y * 8;
    const int vt = blockIdx.x;                    // v-tile: 128 floats = 32 f4

    const float4* attn4 = reinterpret_cast<const float4*>(attn) + (size_t)(b * 64 + q0) * 128;
    const float4* val4  = reinterpret_cast<const float4*>(values) + (size_t)b * 512 * 128 + vt * 32;

    const int lane = t & 63;
    const int w    = t >> 6;       // wave -> q-pair {2w, 2w+1}
    const int v4   = lane & 31;
    const int ksub = lane >> 5;

    float4 rp, rv[8];
    if (t < 128) rp = attn4[(size_t)(t >> 4) * 128 + (t & 15)];
#pragma unroll
    for (int i = 0; i < 8; ++i) {
        int u = t + i * 256;
        rv[i] = val4[(size_t)(u >> 5) * 128 + (u & 31)];
    }

    float4 acc0 = make_float4(0.f, 0.f, 0.f, 0.f);
    float4 acc1 = make_float4(0.f, 0.f, 0.f, 0.f);

    for (int c = 0; c < 8; ++c) {
        __syncthreads();                          // prev chunk's LDS reads done
        if (t < 128)
            *reinterpret_cast<float4*>(&Ps[t >> 4][(t & 15) * 4]) = rp;
#pragma unroll
        for (int i = 0; i < 8; ++i) {
            int u = t + i * 256;
            *reinterpret_cast<float4*>(&Vs[u >> 5][(u & 31) * 4]) = rv[i];
        }
        __syncthreads();
        if (c < 7) {                              // prefetch chunk c+1
            if (t < 128)
                rp = attn4[(size_t)(t >> 4) * 128 + (c + 1) * 16 + (t & 15)];
#pragma unroll
            for (int i = 0; i < 8; ++i) {
                int u = t + i * 256;
                rv[i] = val4[(size_t)((c + 1) * 64 + (u >> 5)) * 128 + (u & 31)];
            }
        }
        // compute: lane covers k = kk*8 + ksub*4 + {0..3}, kk = 0..7
#pragma unroll
        for (int kk = 0; kk < 8; ++kk) {
            int kb = kk * 8 + ksub * 4;
            float4 V0 = *reinterpret_cast<const float4*>(&Vs[kb + 0][v4 * 4]);
            float4 V1 = *reinterpret_cast<const float4*>(&Vs[kb + 1][v4 * 4]);
            float4 V2 = *reinterpret_cast<const float4*>(&Vs[kb + 2][v4 * 4]);
            float4 V3 = *reinterpret_cast<const float4*>(&Vs[kb + 3][v4 * 4]);
            float4 p0 = *reinterpret_cast<const float4*>(&Ps[2 * w][kb]);
            float4 p1 = *reinterpret_cast<const float4*>(&Ps[2 * w + 1][kb]);
            acc0.x = fmaf(p0.x, V0.x, acc0.x); acc0.y = fmaf(p0.x, V0.y, acc0.y);
            acc0.z = fmaf(p0.x, V0.z, acc0.z); acc0.w = fmaf(p0.x, V0.w, acc0.w);
            acc0.x = fmaf(p0.y, V1.x, acc0.x); acc0.y = fmaf(p0.y, V1.y, acc0.y);
            acc0.z = fmaf(p0.y, V1.z, acc0.z); acc0.w = fmaf(p0.y, V1.w, acc0.w);
            acc0.x = fmaf(p0.z, V2.x, acc0.x); acc0.y = fmaf(p0.z, V2.y, acc0.y);
            acc0.z = fmaf(p0.z, V2.z, acc0.z); acc0.w = fmaf(p0.z, V2.w, acc0.w);
            acc0.x = fmaf(p0.w, V3.x, acc0.x); acc0.y = fmaf(p0.w, V3.y, acc0.y);
            acc0.z = fmaf(p0.w, V3.z, acc0.z); acc0.w = fmaf(p0.w, V3.w, acc0.w);
            acc1.x = fmaf(p1.x, V0.x, acc1.x); acc1.y = fmaf(p1.x, V0.y, acc1.y);
            acc1.z = fmaf(p1.x, V0.z, acc1.z); acc1.w = fmaf(p1.x, V0.w, acc1.w);
            acc1.x = fmaf(p1.y, V1.x, acc1.x); acc1.y = fmaf(p1.y, V1.y, acc1.y);
            acc1.z = fmaf(p1.y, V1.z, acc1.z); acc1.w = fmaf(p1.y, V1.w, acc1.w);
            acc1.x = fmaf(p1.z, V2.x, acc1.x); acc1.y = fmaf(p1.z, V2.y, acc1.y);
            acc1.z = fmaf(p1.z, V2.z, acc1.z); acc1.w = fmaf(p1.z, V2.w, acc1.w);
            acc1.x = fmaf(p1.w, V3.x, acc1.x); acc1.y = fmaf(p1.w, V3.y, acc1.y);
            acc1.z = fmaf(p1.w, V3.z, acc1.z); acc1.w = fmaf(p1.w, V3.w, acc1.w);
        }
    }

    // combine ksub partials (butterfly over lane bit 5)
    acc0.x += __shfl_xor(acc0.x, 32); acc0.y += __shfl_xor(acc0.y, 32);
    acc0.z += __shfl_xor(acc0.z, 32); acc0.w += __shfl_xor(acc0.w, 32);
    acc1.x += __shfl_xor(acc1.x, 32); acc1.y += __shfl_xor(acc1.y, 32);
    acc1.z += __shfl_xor(acc1.z, 32); acc1.w += __shfl_xor(acc1.w, 32);
    if (ksub == 0) {
        float4* out4 = reinterpret_cast<float4*>(out);
        out4[(size_t)(b * 64 + q0 + 2 * w) * 128 + vt * 32 + v4]     = acc0;
        out4[(size_t)(b * 64 + q0 + 2 * w + 1) * 128 + vt * 32 + v4] = acc1;
    }
}

// ---------------------------------------------------------------------------
extern "C" void kernel_launch(void* const* d_in, const int* in_sizes, int n_in,
                              void* d_out, int out_size, void* d_ws, size_t ws_size,
                              hipStream_t stream) {
    (void)in_sizes; (void)n_in; (void)out_size; (void)ws_size;
    const float* queries    = (const float*)d_in[0];   // [16,64,512]
    const float* keys       = (const float*)d_in[1];   // [16,512,512]
    const float* values     = (const float*)d_in[2];   // [16,512,512]
    const int*   valid_lens = (const int*)d_in[3];     // [16]
    const float* Wq         = (const float*)d_in[4];   // [512,256]
    const float* Wk         = (const float*)d_in[5];   // [512,256]
    const float* Wv         = (const float*)d_in[6];   // [256]
    float* out = (float*)d_out;                        // [16,64,512]

    float* ws    = (float*)d_ws;
    float* Eq    = ws;                         // [1024][256]        1 MB
    float* Ekp   = ws + 262144;                // [16][128][512][2]  8 MB
    float* attn  = ws + 262144 + 2097152;      // [16][64][512]      2 MB
    ushort* Wq2T = (ushort*)(ws + 2883584);    // [256][1536]        0.75 MB
    ushort* Wk2T = Wq2T + 393216;              // [256][1536]        0.75 MB

    hipLaunchKernelGGL(wprep_kernel, dim3(8, 4, 2), dim3(256), 0, stream,
                       Wq, Wk, Wq2T, Wk2T);
    hipLaunchKernelGGL(mfma_proj_kernel, dim3(288, 2), dim3(256), 0, stream,
                       queries, keys, Wq2T, Wk2T, Eq, Ekp);
    hipLaunchKernelGGL(score_softmax_kernel, dim3(512), dim3(256), 0, stream,
                       Eq, Ekp, Wv, valid_lens, attn);
    hipLaunchKernelGGL(pv_kernel, dim3(4, 8, 16), dim3(256), 0, stream, attn, values, out);
}

// Round 9
// 141.087 us; speedup vs baseline: 1.2903x; 1.2903x over previous
//
#include <hip/hip_runtime.h>

// Problem dims: B=16, Q=64, K=512, DQ=DK=DV=512, H=256
#define LOG2E 1.4426950408889634f
#define TWO_LOG2E 2.8853900817779268f

typedef __attribute__((ext_vector_type(8))) short short8;   // bf16x8 MFMA frag
typedef __attribute__((ext_vector_type(4))) float f32x4;    // MFMA acc

__device__ __forceinline__ float e2x(float v) {
    return __builtin_amdgcn_exp2f(v * TWO_LOG2E);   // e^{2v}
}

// Exact fp32 -> (hi,lo) bf16 split, packed.
__device__ __forceinline__ void split2(float x, float y, unsigned& hi, unsigned& lo) {
    unsigned ux = __float_as_uint(x), uy = __float_as_uint(y);
    float hx = __uint_as_float(ux & 0xffff0000u);
    float hy = __uint_as_float(uy & 0xffff0000u);
    unsigned lx = __float_as_uint(x - hx), ly = __float_as_uint(y - hy);
    hi = (ux >> 16) | (uy & 0xffff0000u);
    lo = (lx >> 16) | (ly & 0xffff0000u);
}

// ---------------------------------------------------------------------------
// Kernel 0: W2T split/transposed weights (unchanged)
// ---------------------------------------------------------------------------
__global__ __launch_bounds__(256) void wprep_kernel(const float* __restrict__ Wq,
                                                    const float* __restrict__ Wk,
                                                    ushort* __restrict__ Wq2T,
                                                    ushort* __restrict__ Wk2T) {
    __shared__ float T[64][65];
    const float* W  = blockIdx.z ? Wk : Wq;
    ushort* W2T     = blockIdx.z ? Wk2T : Wq2T;
    const int t  = threadIdx.x;
    const int k0 = blockIdx.x * 64;
    const int n0 = blockIdx.y * 64;
#pragma unroll
    for (int p = 0; p < 4; ++p) {
        int u  = t + p * 256;
        int kk = u >> 4;
        int nf = (u & 15) * 4;
        float4 w = *reinterpret_cast<const float4*>(&W[(size_t)(k0 + kk) * 256 + n0 + nf]);
        T[nf + 0][kk] = w.x; T[nf + 1][kk] = w.y;
        T[nf + 2][kk] = w.z; T[nf + 3][kk] = w.w;
    }
    __syncthreads();
#pragma unroll
    for (int p = 0; p < 4; ++p) {
        int u  = t + p * 256;
        int n  = u >> 4;
        int kf = (u & 15) * 4;
        float a = T[n][kf], b = T[n][kf + 1], c = T[n][kf + 2], d = T[n][kf + 3];
        unsigned h01, l01, h23, l23;
        split2(a, b, h01, l01);
        split2(c, d, h23, l23);
        int kg = k0 + kf;
        ushort* row = W2T + (size_t)(n0 + n) * 1536 + (kg >> 5) * 96 + (kg & 31);
        uint2 hi; hi.x = h01; hi.y = h23;
        uint2 lo; lo.x = l01; lo.y = l23;
        *reinterpret_cast<uint2*>(row)      = hi;
        *reinterpret_cast<uint2*>(row + 32) = hi;
        *reinterpret_cast<uint2*>(row + 64) = lo;
    }
}

// ---------------------------------------------------------------------------
// Kernel 1: fused MFMA projection (unchanged from round 8)
// ---------------------------------------------------------------------------
__global__ __launch_bounds__(256) void mfma_proj_kernel(const float* __restrict__ queries,
                                                        const float* __restrict__ keys,
                                                        const ushort* __restrict__ Wq2T,
                                                        const ushort* __restrict__ Wk2T,
                                                        float* __restrict__ Eq,
                                                        float* __restrict__ Ekp) {
    __shared__ float smemf[7680];
    ushort* Ah = reinterpret_cast<ushort*>(smemf);           // [32 m][96 k']
    ushort* Ws = reinterpret_cast<ushort*>(smemf) + 3072;    // [128 n][96 k']

    const int t    = threadIdx.x;
    const int mt   = blockIdx.x;
    const int Nb   = blockIdx.y * 128;
    const bool isQ = mt < 32;
    const int mloc = (isQ ? mt : mt - 32) * 32;
    const float4* Asrc4 = reinterpret_cast<const float4*>(isQ ? queries : keys)
                        + (size_t)mloc * 128;
    const ushort* W2T = isQ ? Wq2T : Wk2T;

    const int ln15 = t & 15;
    const int q    = (t >> 4) & 3;
    const int w    = t >> 6;
    const int wn   = w * 32;

    const char* gB[6];
#pragma unroll
    for (int i = 0; i < 6; ++i) {
        int o   = i * 4096 + t * 16;
        int row = o / 192;
        int rem = o - row * 192;
        gB[i] = reinterpret_cast<const char*>(W2T) + (size_t)(Nb + row) * 3072 + rem;
    }

    f32x4 acc[2][2];
#pragma unroll
    for (int fm = 0; fm < 2; ++fm)
#pragma unroll
        for (int fn = 0; fn < 2; ++fn) acc[fm][fn] = (f32x4)0.0f;

    for (int c = 0; c < 16; ++c) {
        __syncthreads();
        {
            int m  = t >> 3;
            int kf = (t & 7) * 4;
            float4 a = Asrc4[(size_t)m * 128 + c * 8 + (t & 7)];
            unsigned h01, l01, h23, l23;
            split2(a.x, a.y, h01, l01);
            split2(a.z, a.w, h23, l23);
            uint2 hi; hi.x = h01; hi.y = h23;
            uint2 lo; lo.x = l01; lo.y = l23;
            ushort* row = Ah + m * 96 + kf;
            *reinterpret_cast<uint2*>(row)      = hi;
            *reinterpret_cast<uint2*>(row + 32) = lo;
            *reinterpret_cast<uint2*>(row + 64) = hi;
        }
#pragma unroll
        for (int i = 0; i < 6; ++i) {
            __builtin_amdgcn_global_load_lds(
                reinterpret_cast<const unsigned int*>(gB[i]),
                reinterpret_cast<unsigned int*>(
                    reinterpret_cast<char*>(Ah) + 6144 + i * 4096 + (t >> 6) * 1024),
                16, 0, 0);
            gB[i] += 192;
        }
        __syncthreads();
#pragma unroll
        for (int s = 0; s < 3; ++s) {
            short8 af[2], bf[2];
#pragma unroll
            for (int fm = 0; fm < 2; ++fm)
                af[fm] = *reinterpret_cast<const short8*>(
                    Ah + (fm * 16 + ln15) * 96 + s * 32 + q * 8);
#pragma unroll
            for (int fn = 0; fn < 2; ++fn)
                bf[fn] = *reinterpret_cast<const short8*>(
                    Ws + (wn + fn * 16 + ln15) * 96 + s * 32 + q * 8);
#pragma unroll
            for (int fm = 0; fm < 2; ++fm)
#pragma unroll
                for (int fn = 0; fn < 2; ++fn)
                    acc[fm][fn] = __builtin_amdgcn_mfma_f32_16x16x32_bf16(
                        af[fm], bf[fn], acc[fm][fn], 0, 0, 0);
        }
    }

    if (isQ) {
#pragma unroll
        for (int fm = 0; fm < 2; ++fm)
#pragma unroll
            for (int fn = 0; fn < 2; ++fn)
#pragma unroll
                for (int r = 0; r < 4; ++r) {
                    int row = mloc + fm * 16 + q * 4 + r;
                    int col = Nb + wn + fn * 16 + ln15;
                    Eq[(size_t)row * 256 + col] = e2x(acc[fm][fn][r]);
                }
    } else {
        __syncthreads();
        float (*Cs)[33] = reinterpret_cast<float(*)[33]>(smemf);  // [n 128][m 32]
#pragma unroll
        for (int fm = 0; fm < 2; ++fm)
#pragma unroll
            for (int fn = 0; fn < 2; ++fn)
#pragma unroll
                for (int r = 0; r < 4; ++r) {
                    int m_l = fm * 16 + q * 4 + r;
                    int n_l = wn + fn * 16 + ln15;
                    Cs[n_l][m_l] = acc[fm][fn][r];
                }
        __syncthreads();
        const int b      = mloc >> 9;
        const int k0h    = (mloc & 511) >> 1;
        const int h2base = Nb >> 1;
        float4* out4 = reinterpret_cast<float4*>(Ekp);
#pragma unroll
        for (int p = 0; p < 4; ++p) {
            int u   = t + p * 256;
            int h2r = u >> 4;
            int kp  = u & 15;
            int kk  = kp * 2;
            float4 o;
            o.x = e2x(Cs[2 * h2r    ][kk    ]);
            o.y = e2x(Cs[2 * h2r + 1][kk    ]);
            o.z = e2x(Cs[2 * h2r    ][kk + 1]);
            o.w = e2x(Cs[2 * h2r + 1][kk + 1]);
            out4[(size_t)b * 32768 + (size_t)(h2base + h2r) * 256 + k0h + kp] = o;
        }
    }
}

// ---------------------------------------------------------------------------
// Kernel 2: scores + masked softmax -> attn[b][q][k]   (unchanged)
// ---------------------------------------------------------------------------
__global__ __launch_bounds__(256) void score_softmax_kernel(
        const float* __restrict__ Eq, const float* __restrict__ Ekp,
        const float* __restrict__ Wv, const int* __restrict__ valid_lens,
        float* __restrict__ attn) {
    __shared__ float redmA[4], redmB[4], redlA[4], redlB[4];

    const int t  = threadIdx.x;
    const int bq = blockIdx.x;
    const int b  = bq >> 5;
    const int q0 = (bq & 31) * 2;

    const float* eqA = Eq + (size_t)(b * 64 + q0) * 256;
    const float* eqB = eqA + 256;
    const float4* ek4 = reinterpret_cast<const float4*>(Ekp) + (size_t)b * 32768 + t;

    float accA0 = 0.f, accA1 = 0.f, accB0 = 0.f, accB1 = 0.f;
#pragma unroll 4
    for (int h2 = 0; h2 < 128; ++h2) {
        const float4 ek = ek4[h2 * 256];
        const float w0 = Wv[2 * h2];
        const float w1 = Wv[2 * h2 + 1];
        {
            const float e0 = eqA[2 * h2], e1 = eqA[2 * h2 + 1];
            float a00 = fmaf(e0, ek.x, 1.0f);
            float a10 = fmaf(e1, ek.y, 1.0f);
            float a01 = fmaf(e0, ek.z, 1.0f);
            float a11 = fmaf(e1, ek.w, 1.0f);
            float d0 = a00 * a10, d1 = a01 * a11;
            float n0 = fmaf(w1, a00, w0 * a10);
            float n1 = fmaf(w1, a01, w0 * a11);
            accA0 = fmaf(n0, __builtin_amdgcn_rcpf(d0), accA0);
            accA1 = fmaf(n1, __builtin_amdgcn_rcpf(d1), accA1);
        }
        {
            const float e0 = eqB[2 * h2], e1 = eqB[2 * h2 + 1];
            float a00 = fmaf(e0, ek.x, 1.0f);
            float a10 = fmaf(e1, ek.y, 1.0f);
            float a01 = fmaf(e0, ek.z, 1.0f);
            float a11 = fmaf(e1, ek.w, 1.0f);
            float d0 = a00 * a10, d1 = a01 * a11;
            float n0 = fmaf(w1, a00, w0 * a10);
            float n1 = fmaf(w1, a01, w0 * a11);
            accB0 = fmaf(n0, __builtin_amdgcn_rcpf(d0), accB0);
            accB1 = fmaf(n1, __builtin_amdgcn_rcpf(d1), accB1);
        }
    }
    float sA0 = -2.0f * accA0, sA1 = -2.0f * accA1;
    float sB0 = -2.0f * accB0, sB1 = -2.0f * accB1;
    const int vl = valid_lens[b];
    const int k0 = 2 * t;
    if (k0     >= vl) { sA0 = -1e6f; sB0 = -1e6f; }
    if (k0 + 1 >= vl) { sA1 = -1e6f; sB1 = -1e6f; }

    const int w = t >> 6;
    float mA = fmaxf(sA0, sA1);
    float mB = fmaxf(sB0, sB1);
#pragma unroll
    for (int off = 32; off > 0; off >>= 1) {
        mA = fmaxf(mA, __shfl_xor(mA, off));
        mB = fmaxf(mB, __shfl_xor(mB, off));
    }
    if ((t & 63) == 0) { redmA[w] = mA; redmB[w] = mB; }
    __syncthreads();
    mA = fmaxf(fmaxf(redmA[0], redmA[1]), fmaxf(redmA[2], redmA[3]));
    mB = fmaxf(fmaxf(redmB[0], redmB[1]), fmaxf(redmB[2], redmB[3]));

    float pA0 = __builtin_amdgcn_exp2f((sA0 - mA) * LOG2E);
    float pA1 = __builtin_amdgcn_exp2f((sA1 - mA) * LOG2E);
    float pB0 = __builtin_amdgcn_exp2f((sB0 - mB) * LOG2E);
    float pB1 = __builtin_amdgcn_exp2f((sB1 - mB) * LOG2E);
    float lA = pA0 + pA1, lB = pB0 + pB1;
#pragma unroll
    for (int off = 32; off > 0; off >>= 1) {
        lA += __shfl_xor(lA, off);
        lB += __shfl_xor(lB, off);
    }
    if ((t & 63) == 0) { redlA[w] = lA; redlB[w] = lB; }
    __syncthreads();
    lA = (redlA[0] + redlA[1]) + (redlA[2] + redlA[3]);
    lB = (redlB[0] + redlB[1]) + (redlB[2] + redlB[3]);
    const float invA = 1.0f / lA;
    const float invB = 1.0f / lB;

    float2* attn2 = reinterpret_cast<float2*>(attn);
    float2 oA; oA.x = pA0 * invA; oA.y = pA1 * invA;
    float2 oB; oB.x = pB0 * invB; oB.y = pB1 * invB;
    attn2[(size_t)(b * 64 + q0) * 256 + t]       = oA;
    attn2[(size_t)(b * 64 + q0 + 1) * 256 + t]   = oB;
}

// ---------------------------------------------------------------------------
// Kernel 3 (REBUILT, no register prefetch -> no spills):
// out[b][q][v] = attn[b][q][:] @ values[b][:][v]
// Block = (b, 8q, 128v); grid (4, 8, 16) = 512 (2/CU, 3 resident by LDS).
// Ps[8][516] staged ONCE (full K). Per 64-k chunk: Vs[64][128] (32 KB)
// filled by 8x global_load_lds(16B) -> zero VGPR staging cost; m97-style
// 2-barrier chunk loop; cross-block overlap hides the drain.
// Lane = (v4 0..31, ksub 0..1), wave = q-pair; shfl_xor(32) combine.
// ---------------------------------------------------------------------------
__global__ __launch_bounds__(256) void pv_kernel(const float* __restrict__ attn,
                                                 const float* __restrict__ values,
                                                 float* __restrict__ out) {
    __shared__ __align__(16) float Ps[8][516];   // 16512 B, staged once
    __shared__ __align__(16) float Vs[64][128];  // 32768 B, per chunk

    const int t  = threadIdx.x;
    const int b  = blockIdx.z;
    const int q0 = blockIdx.y * 8;
    const int vt = blockIdx.x;                   // v-tile: 128 floats

    // ---- stage ALL of P once: 8 q-rows x 512 k ----
    const float4* attn4 = reinterpret_cast<const float4*>(attn) + (size_t)(b * 64 + q0) * 128;
#pragma unroll
    for (int p = 0; p < 4; ++p) {
        int u  = t + p * 256;                    // 0..1023
        int qr = u >> 7;                         // 0..7
        int c4 = u & 127;                        // 0..127
        *reinterpret_cast<float4*>(&Ps[qr][c4 * 4]) = attn4[(size_t)qr * 128 + c4];
    }

    // ---- V staging pointers: chunk c call i writes Vs bytes [i*4096 + t*16) ----
    // linear o = i*4096 + t*16; k-row = o>>9, byte-in-row = o&511
    const char* vbase = reinterpret_cast<const char*>(values)
                      + ((size_t)b * 512 * 512 + (size_t)vt * 128) * 4   // batch + v-tile
                      + (size_t)(t >> 5) * 2048 + (size_t)(t & 31) * 16; // k=(t>>5), voff
    char* ldsV = reinterpret_cast<char*>(&Vs[0][0]) + (t >> 6) * 1024;

    const int lane = t & 63;
    const int w    = t >> 6;                     // wave -> q-pair {2w, 2w+1}
    const int v4   = lane & 31;
    const int ksub = lane >> 5;

    float4 acc0 = make_float4(0.f, 0.f, 0.f, 0.f);
    float4 acc1 = make_float4(0.f, 0.f, 0.f, 0.f);

    for (int c = 0; c < 8; ++c) {
        // issue chunk-c V loads (Vs free: reads of chunk c-1 completed at the
        // second barrier of the previous iteration)
#pragma unroll
        for (int i = 0; i < 8; ++i) {
            __builtin_amdgcn_global_load_lds(
                reinterpret_cast<const unsigned int*>(
                    vbase + (size_t)c * 131072 + (size_t)i * 8 * 2048),
                reinterpret_cast<unsigned int*>(ldsV + i * 4096),
                16, 0, 0);
        }
        __syncthreads();                         // drains vmcnt: Vs ready (+Ps on c=0)

        const float* pr0 = &Ps[2 * w][c * 64];
        const float* pr1 = &Ps[2 * w + 1][c * 64];
#pragma unroll
        for (int kk = 0; kk < 8; ++kk) {
            int kb = kk * 8 + ksub * 4;
            float4 V0 = *reinterpret_cast<const float4*>(&Vs[kb + 0][v4 * 4]);
            float4 V1 = *reinterpret_cast<const float4*>(&Vs[kb + 1][v4 * 4]);
            float4 V2 = *reinterpret_cast<const float4*>(&Vs[kb + 2][v4 * 4]);
            float4 V3 = *reinterpret_cast<const float4*>(&Vs[kb + 3][v4 * 4]);
            float4 p0 = *reinterpret_cast<const float4*>(&pr0[kb]);
            float4 p1 = *reinterpret_cast<const float4*>(&pr1[kb]);
            acc0.x = fmaf(p0.x, V0.x, acc0.x); acc0.y = fmaf(p0.x, V0.y, acc0.y);
            acc0.z = fmaf(p0.x, V0.z, acc0.z); acc0.w = fmaf(p0.x, V0.w, acc0.w);
            acc0.x = fmaf(p0.y, V1.x, acc0.x); acc0.y = fmaf(p0.y, V1.y, acc0.y);
            acc0.z = fmaf(p0.y, V1.z, acc0.z); acc0.w = fmaf(p0.y, V1.w, acc0.w);
            acc0.x = fmaf(p0.z, V2.x, acc0.x); acc0.y = fmaf(p0.z, V2.y, acc0.y);
            acc0.z = fmaf(p0.z, V2.z, acc0.z); acc0.w = fmaf(p0.z, V2.w, acc0.w);
            acc0.x = fmaf(p0.w, V3.x, acc0.x); acc0.y = fmaf(p0.w, V3.y, acc0.y);
            acc0.z = fmaf(p0.w, V3.z, acc0.z); acc0.w = fmaf(p0.w, V3.w, acc0.w);
            acc1.x = fmaf(p1.x, V0.x, acc1.x); acc1.y = fmaf(p1.x, V0.y, acc1.y);
            acc1.z = fmaf(p1.x, V0.z, acc1.z); acc1.w = fmaf(p1.x, V0.w, acc1.w);
            acc1.x = fmaf(p1.y, V1.x, acc1.x); acc1.y = fmaf(p1.y, V1.y, acc1.y);
            acc1.z = fmaf(p1.y, V1.z, acc1.z); acc1.w = fmaf(p1.y, V1.w, acc1.w);
            acc1.x = fmaf(p1.z, V2.x, acc1.x); acc1.y = fmaf(p1.z, V2.y, acc1.y);
            acc1.z = fmaf(p1.z, V2.z, acc1.z); acc1.w = fmaf(p1.z, V2.w, acc1.w);
            acc1.x = fmaf(p1.w, V3.x, acc1.x); acc1.y = fmaf(p1.w, V3.y, acc1.y);
            acc1.z = fmaf(p1.w, V3.z, acc1.z); acc1.w = fmaf(p1.w, V3.w, acc1.w);
        }
        __syncthreads();                         // all reads of chunk c done
    }

    // combine ksub partials (butterfly over lane bit 5)
    acc0.x += __shfl_xor(acc0.x, 32); acc0.y += __shfl_xor(acc0.y, 32);
    acc0.z += __shfl_xor(acc0.z, 32); acc0.w += __shfl_xor(acc0.w, 32);
    acc1.x += __shfl_xor(acc1.x, 32); acc1.y += __shfl_xor(acc1.y, 32);
    acc1.z += __shfl_xor(acc1.z, 32); acc1.w += __shfl_xor(acc1.w, 32);
    if (ksub == 0) {
        float4* out4 = reinterpret_cast<float4*>(out);
        out4[(size_t)(b * 64 + q0 + 2 * w) * 128 + vt * 32 + v4]     = acc0;
        out4[(size_t)(b * 64 + q0 + 2 * w + 1) * 128 + vt * 32 + v4] = acc1;
    }
}

// ---------------------------------------------------------------------------
extern "C" void kernel_launch(void* const* d_in, const int* in_sizes, int n_in,
                              void* d_out, int out_size, void* d_ws, size_t ws_size,
                              hipStream_t stream) {
    (void)in_sizes; (void)n_in; (void)out_size; (void)ws_size;
    const float* queries    = (const float*)d_in[0];   // [16,64,512]
    const float* keys       = (const float*)d_in[1];   // [16,512,512]
    const float* values     = (const float*)d_in[2];   // [16,512,512]
    const int*   valid_lens = (const int*)d_in[3];     // [16]
    const float* Wq         = (const float*)d_in[4];   // [512,256]
    const float* Wk         = (const float*)d_in[5];   // [512,256]
    const float* Wv         = (const float*)d_in[6];   // [256]
    float* out = (float*)d_out;                        // [16,64,512]

    float* ws    = (float*)d_ws;
    float* Eq    = ws;                         // [1024][256]        1 MB
    float* Ekp   = ws + 262144;                // [16][128][512][2]  8 MB
    float* attn  = ws + 262144 + 2097152;      // [16][64][512]      2 MB
    ushort* Wq2T = (ushort*)(ws + 2883584);    // [256][1536]        0.75 MB
    ushort* Wk2T = Wq2T + 393216;              // [256][1536]        0.75 MB

    hipLaunchKernelGGL(wprep_kernel, dim3(8, 4, 2), dim3(256), 0, stream,
                       Wq, Wk, Wq2T, Wk2T);
    hipLaunchKernelGGL(mfma_proj_kernel, dim3(288, 2), dim3(256), 0, stream,
                       queries, keys, Wq2T, Wk2T, Eq, Ekp);
    hipLaunchKernelGGL(score_softmax_kernel, dim3(512), dim3(256), 0, stream,
                       Eq, Ekp, Wv, valid_lens, attn);
    hipLaunchKernelGGL(pv_kernel, dim3(4, 8, 16), dim3(256), 0, stream, attn, values, out);
}